// Round 14
// baseline (525.646 us; speedup 1.0000x reference)
//
#include <hip/hip_runtime.h>

typedef unsigned short u16;
typedef unsigned int u32;

#define HDIM 180
#define HW 32400
#define CC 128

// canon element offsets (bf16), same map as proven R2 build
#define CAN_SRC   0
#define CAN_REF   12441600
#define CAN_CW    12636000
#define CAN_CB    12930912
#define CAN_WVAL  12931040
#define CAN_BVAL  12947424
#define CAN_WOFF  12947552
#define CAN_BOFF  12955744
#define CAN_WATTN 12955808
#define CAN_BATTN 12959904
#define CAN_WOUT  12959936
#define CAN_BOUT  12976320
#define CAN_LN1G  12976448
#define CAN_LN1B  12976576
#define CAN_W1    12976704
#define CAN_B1    13107776
#define CAN_W2    13108800
#define CAN_B2    13239872
#define CAN_LN2G  13240000
#define CAN_LN2B  13240128
#define CAN_TOTAL 13240256

typedef short short8 __attribute__((ext_vector_type(8)));
typedef float f32x4v __attribute__((ext_vector_type(4)));

__device__ __forceinline__ float bf2f(u16 v) { return __uint_as_float(((u32)v) << 16); }
__device__ __forceinline__ u16 f2bf(float f) {
    u32 x = __float_as_uint(f);
    return (u16)((x + 0x7FFFu + ((x >> 16) & 1u)) >> 16);
}
__device__ __forceinline__ void bf8_to_f(const uint4 v, float* o) {
    o[0] = __uint_as_float(v.x << 16); o[1] = __uint_as_float(v.x & 0xFFFF0000u);
    o[2] = __uint_as_float(v.y << 16); o[3] = __uint_as_float(v.y & 0xFFFF0000u);
    o[4] = __uint_as_float(v.z << 16); o[5] = __uint_as_float(v.z & 0xFFFF0000u);
    o[6] = __uint_as_float(v.w << 16); o[7] = __uint_as_float(v.w & 0xFFFF0000u);
}

// ---------------------------------------------------------------------------
// Canonicalize src/ref/weights to bf16.
// ---------------------------------------------------------------------------
struct PtrsZ { const void* p[20]; };

__global__ __launch_bounds__(256) void convert_z(PtrsZ ptrs, u16* __restrict__ out)
{
    const int offs[20] = {CAN_SRC, CAN_REF, CAN_CW, CAN_CB, CAN_WVAL, CAN_BVAL,
                          CAN_WOFF, CAN_BOFF, CAN_WATTN, CAN_BATTN, CAN_WOUT, CAN_BOUT,
                          CAN_LN1G, CAN_LN1B, CAN_W1, CAN_B1, CAN_W2, CAN_B2,
                          CAN_LN2G, CAN_LN2B};
    int gid = blockIdx.x * 256 + threadIdx.x;
    if (gid >= CAN_TOTAL) return;
    int t = 0;
    #pragma unroll
    for (int i = 1; i < 20; i++) t += (gid >= offs[i]) ? 1 : 0;
    int e = gid - offs[t];
    bool isb = (*(const u32*)ptrs.p[12]) == 0x3F803F80u;   // ln1_g
    out[gid] = isb ? ((const u16*)ptrs.p[t])[e] : f2bf(((const float*)ptrs.p[t])[e]);
}

// ---------------------------------------------------------------------------
// Merged prep: conv-wt transpose + WvalT + Wcat/b128 + WoutT (one launch).
// ---------------------------------------------------------------------------
__global__ __launch_bounds__(256) void prep1_z(
    const u16* __restrict__ cw, const u16* __restrict__ wval, const u16* __restrict__ wout,
    const u16* __restrict__ woff, const u16* __restrict__ wattn,
    const u16* __restrict__ boff, const u16* __restrict__ battn,
    u16* __restrict__ wtbuf, u16* __restrict__ wvalT,
    u16* __restrict__ wcat, u16* __restrict__ b128, u16* __restrict__ woutT)
{
    int gid = blockIdx.x * 256 + threadIdx.x;
    if (gid < 294912) {                       // conv wt[half][tap][co][ci]
        int ci = gid & 127, co = (gid >> 7) & 127, rest = gid >> 14;
        int tap = rest % 9, half = rest / 9;
        wtbuf[gid] = cw[(size_t)co * 2304 + (half * 128 + ci) * 9 + tap];
    } else if (gid < 311296) {                // WvalT[n][k]
        int e = gid - 294912;
        int k = e >> 7, n = e & 127;
        wvalT[n * 128 + k] = wval[e];
    } else if (gid < 327808) {                // WcatT + b128
        int e = gid - 311296;
        if (e < 16384) {
            int n = e >> 7, k = e & 127;
            u16 v = 0;
            if (n < 64) v = woff[k * 64 + n];
            else if (n < 96) v = wattn[k * 32 + (n - 64)];
            wcat[n * 128 + k] = v;
        } else {
            int n = e - 16384;
            u16 v = 0;
            if (n < 64) v = boff[n]; else if (n < 96) v = battn[n - 64];
            b128[n] = v;
        }
    } else if (gid < 344192) {                // WoutT[n][k]
        int e = gid - 327808;
        int k = e >> 7, n = e & 127;
        woutT[n * 128 + k] = wout[e];
    }
}

// W1T/W2T (after value is dead)
__global__ __launch_bounds__(256) void w12t_z(
    const u16* __restrict__ w1, const u16* __restrict__ w2,
    u16* __restrict__ w1t, u16* __restrict__ w2t)
{
    int gid = blockIdx.x * 256 + threadIdx.x;
    if (gid < 131072) {                       // W1 [128][1024]
        int k = gid >> 10, n = gid & 1023;
        w1t[(size_t)n * 128 + k] = w1[gid];
    } else if (gid < 262144) {                // W2 [1024][128]
        int e = gid - 131072;
        int k = e >> 7, n = e & 127;
        w2t[(size_t)n * 1024 + k] = w2[e];
    }
}

// ---------------------------------------------------------------------------
// FALLBACK tiled VALU GEMM (small-ws path only).
// ---------------------------------------------------------------------------
template<bool OUT_BF16, bool RELU, bool RES>
__global__ __launch_bounds__(256) void gemm_z(
    const u16* __restrict__ A, const u16* __restrict__ W, const u16* __restrict__ bias,
    void* __restrict__ outp, const u16* __restrict__ res, int M, int N, int K)
{
    __shared__ float As[64][68];
    __shared__ float Bs[64][68];
    const int tid = threadIdx.x;
    const int tx = tid & 15, ty = tid >> 4;
    const int m0 = blockIdx.y * 64, n0 = blockIdx.x * 64;
    float acc[4][4] = {};

    for (int k0 = 0; k0 < K; k0 += 64) {
        __syncthreads();
        #pragma unroll
        for (int i = tid; i < 512; i += 256) {
            int row = i >> 3, part = i & 7;
            float f[8];
            if (m0 + row < M) {
                uint4 v = *(const uint4*)(A + (size_t)(m0 + row) * K + k0 + part * 8);
                bf8_to_f(v, f);
            } else {
                #pragma unroll
                for (int j = 0; j < 8; j++) f[j] = 0.f;
            }
            #pragma unroll
            for (int j = 0; j < 8; j++) As[part * 8 + j][row] = f[j];
        }
        #pragma unroll
        for (int i = tid; i < 512; i += 256) {
            int kr = i >> 3, np = i & 7;
            float f[8];
            uint4 v = *(const uint4*)(W + (size_t)(k0 + kr) * N + n0 + np * 8);
            bf8_to_f(v, f);
            #pragma unroll
            for (int j = 0; j < 8; j++) Bs[kr][np * 8 + j] = f[j];
        }
        __syncthreads();
        #pragma unroll 8
        for (int kk = 0; kk < 64; kk++) {
            float4 a = *(const float4*)&As[kk][ty * 4];
            float4 b = *(const float4*)&Bs[kk][tx * 4];
            float av[4] = {a.x, a.y, a.z, a.w};
            float bv[4] = {b.x, b.y, b.z, b.w};
            #pragma unroll
            for (int i = 0; i < 4; i++)
                #pragma unroll
                for (int j = 0; j < 4; j++)
                    acc[i][j] += av[i] * bv[j];
        }
    }

    #pragma unroll
    for (int i = 0; i < 4; i++) {
        int row = m0 + ty * 4 + i;
        if (row >= M) continue;
        #pragma unroll
        for (int j = 0; j < 4; j++) {
            int col = n0 + tx * 4 + j;
            float v = acc[i][j] + bf2f(bias[col]);
            if (RELU) v = v > 0.f ? v : 0.f;
            if (RES) v += bf2f(res[(size_t)row * N + col]);
            if (OUT_BF16) ((u16*)outp)[(size_t)row * N + col] = f2bf(v);
            else          ((float*)outp)[(size_t)row * N + col] = v;
        }
    }
}

// ---------------------------------------------------------------------------
// FALLBACK (small ws): 3x3 SAME conv, f32 VALU version (R2-proven).
// ---------------------------------------------------------------------------
__global__ __launch_bounds__(256) void conv_z(
    const u16* __restrict__ src, const u16* __restrict__ cw, const u16* __restrict__ cb,
    u16* __restrict__ queries)
{
    __shared__ float in_lds[8 * 6 * 22];
    __shared__ float w_lds[8 * 9 * 128];
    const int tid = threadIdx.x;
    const int wt = blockIdx.x, ht = blockIdx.y, l = blockIdx.z;
    const int h0 = ht * 4, w0 = wt * 20;
    const int cog = tid & 15, pxg = tid >> 4;
    const int pr = pxg >> 2, c0 = (pxg & 3) * 5;

    float acc[5][8] = {};

    for (int ch = 0; ch < 32; ch++) {
        const int ci0 = ch * 8;
        const int fsel = (ci0 < 128) ? 0 : l;
        const int cbase = ci0 & 127;
        __syncthreads();
        if (tid < 132) {
            int r = tid / 22, c = tid % 22;
            int gh = h0 - 1 + r, gw = w0 - 1 + c;
            float f[8];
            if (gh >= 0 && gh < HDIM && gw >= 0 && gw < HDIM) {
                uint4 v = *(const uint4*)(src + ((size_t)fsel * HW + gh * HDIM + gw) * CC + cbase);
                bf8_to_f(v, f);
            } else {
                #pragma unroll
                for (int j = 0; j < 8; j++) f[j] = 0.f;
            }
            #pragma unroll
            for (int j = 0; j < 8; j++) in_lds[j * 132 + r * 22 + c] = f[j];
        }
        for (int i = tid; i < 1152; i += 256) {
            int co = i & 127, part = i >> 7;
            uint4 v = *(const uint4*)(cw + (size_t)co * 2304 + ci0 * 9 + part * 8);
            float f[8]; bf8_to_f(v, f);
            #pragma unroll
            for (int j = 0; j < 8; j++) {
                int flat = part * 8 + j;
                int ci = flat / 9, k = flat % 9;
                w_lds[ci * 1152 + k * 128 + co] = f[j];
            }
        }
        __syncthreads();

        #pragma unroll
        for (int ci = 0; ci < 8; ci++) {
            float xv[3][7];
            #pragma unroll
            for (int r = 0; r < 3; r++)
                #pragma unroll
                for (int c = 0; c < 7; c++)
                    xv[r][c] = in_lds[ci * 132 + (pr + r) * 22 + (c0 + c)];
            const float* wbase = &w_lds[ci * 1152];
            #pragma unroll
            for (int j8 = 0; j8 < 8; j8++) {
                int co = cog + 16 * j8;
                float w_[9];
                #pragma unroll
                for (int k = 0; k < 9; k++) w_[k] = wbase[k * 128 + co];
                #pragma unroll
                for (int j = 0; j < 5; j++) {
                    acc[j][j8] += xv[0][j] * w_[0] + xv[0][j + 1] * w_[1] + xv[0][j + 2] * w_[2]
                                + xv[1][j] * w_[3] + xv[1][j + 1] * w_[4] + xv[1][j + 2] * w_[5]
                                + xv[2][j] * w_[6] + xv[2][j + 1] * w_[7] + xv[2][j + 2] * w_[8];
                }
            }
        }
    }

    float bias[8];
    #pragma unroll
    for (int j8 = 0; j8 < 8; j8++) bias[j8] = bf2f(cb[cog + 16 * j8]);
    #pragma unroll
    for (int j = 0; j < 5; j++) {
        int q = (h0 + pr) * HDIM + (w0 + c0 + j);
        u16* qp = queries + ((size_t)l * HW + q) * CC;
        #pragma unroll
        for (int j8 = 0; j8 < 8; j8++)
            qp[cog + 16 * j8] = f2bf(acc[j][j8] + bias[j8]);
    }
}

// ---------------------------------------------------------------------------
// conv as implicit GEMM, v8: half-factored, SUBT sub-tiles/wave.
// MODE 0 (SUBT=2, grid 254 = balanced): frame-0 half once -> q0.
// MODE 1 (SUBT=3, grid 507 = 1.98/CU): per-l half; acc from q0; -> queries.
// q0 indexed by GLOBAL fragment-block pb = pixel/16 -> layouts compatible.
// Double-buffered weight staging (T14 split), fragment-order LDS.
// ---------------------------------------------------------------------------
template<int MODE, int SUBT>
__global__ __launch_bounds__(256) void convh_z(
    const u16* __restrict__ src, const u16* __restrict__ wt, const u16* __restrict__ cb,
    f32x4v* __restrict__ q0, u16* __restrict__ queries)
{
    __shared__ uint4 Blds[2][2048];   // 64 KB total, double-buffered
    const int tid = threadIdx.x;
    const int wv = tid >> 6, ln = tid & 63;
    const int lo = ln & 15, hi = ln >> 4;
    const int l = (MODE == 1) ? blockIdx.y : 0;
    const int pix0 = blockIdx.x * (SUBT * 64) + wv * (SUBT * 16);
    const int pb0 = blockIdx.x * (SUBT * 4) + wv * SUBT;

    int ph[SUBT], pc[SUBT];
    #pragma unroll
    for (int s = 0; s < SUBT; s++) {
        int p = pix0 + s * 16 + lo;
        ph[s] = p / HDIM; pc[s] = p % HDIM;        // tail OOB: loads/stores gated
    }

    f32x4v acc[SUBT][8];
    if (MODE == 0) {
        #pragma unroll
        for (int s = 0; s < SUBT; s++)
            #pragma unroll
            for (int c = 0; c < 8; c++) acc[s][c] = (f32x4v){0.f, 0.f, 0.f, 0.f};
    } else {
        #pragma unroll
        for (int s = 0; s < SUBT; s++)
            #pragma unroll
            for (int c = 0; c < 8; c++)
                acc[s][c] = q0[((size_t)(pb0 + s) * 8 + c) * 64 + ln];
    }

    const u16* wthalf = wt + (MODE == 1 ? (size_t)9 * 16384 : 0);
    const u16* sbase  = src + (MODE == 1 ? (size_t)l * HW * CC : 0);

    const int sco = tid >> 1, spart = tid & 1;     // staging coords
    const int sc8 = sco >> 4, slo = sco & 15;

    // prologue: stage tile 0 into buffer 0
    {
        const uint4* g = (const uint4*)(wthalf + (size_t)sco * 128 + spart * 64);
        uint4 gr[8];
        #pragma unroll
        for (int i = 0; i < 8; i++) gr[i] = g[i];
        #pragma unroll
        for (int i = 0; i < 8; i++) {
            int k8 = spart * 8 + i;
            Blds[0][((k8 >> 2) * 8 + sc8) * 64 + (k8 & 3) * 16 + slo] = gr[i];
        }
    }
    __syncthreads();

    for (int t = 0; t < 9; t++) {
        const int cur = t & 1;

        // (1) issue next tile's global loads (latency hides under MFMAs)
        uint4 gr[8];
        if (t < 8) {
            const uint4* g = (const uint4*)(wthalf + (size_t)(t + 1) * 16384 +
                                            (size_t)sco * 128 + spart * 64);
            #pragma unroll
            for (int i = 0; i < 8; i++) gr[i] = g[i];
        }

        // (2) MFMA section on current buffer
        const int dy = t / 3 - 1, dx = t % 3 - 1;
        bool vld[SUBT];
        const u16* arow[SUBT];
        #pragma unroll
        for (int s = 0; s < SUBT; s++) {
            int sh = ph[s] + dy, sc = pc[s] + dx;
            vld[s] = (sh >= 0) && (sh < HDIM) && (sc >= 0) && (sc < HDIM);
            arow[s] = sbase + (size_t)(sh * HDIM + sc) * CC;
        }

        #pragma unroll
        for (int kc = 0; kc < 4; kc++) {
            short8 aa[SUBT];
            #pragma unroll
            for (int s = 0; s < SUBT; s++) {
                aa[s] = (short8){};
                if (vld[s]) aa[s] = *(const short8*)(arow[s] + kc * 32 + hi * 8);
            }
            #pragma unroll
            for (int c = 0; c < 8; c++) {
                short8 b = ((const short8*)&Blds[cur][0])[(kc * 8 + c) * 64 + ln];
                #pragma unroll
                for (int s = 0; s < SUBT; s++)
                    acc[s][c] = __builtin_amdgcn_mfma_f32_16x16x32_bf16(aa[s], b, acc[s][c], 0, 0, 0);
            }
        }

        // (3) write-late: next tile regs -> other buffer
        if (t < 8) {
            #pragma unroll
            for (int i = 0; i < 8; i++) {
                int k8 = spart * 8 + i;
                Blds[cur ^ 1][((k8 >> 2) * 8 + sc8) * 64 + (k8 & 3) * 16 + slo] = gr[i];
            }
        }
        __syncthreads();   // one barrier per round
    }

    if (MODE == 0) {
        #pragma unroll
        for (int s = 0; s < SUBT; s++)
            #pragma unroll
            for (int c = 0; c < 8; c++)
                q0[((size_t)(pb0 + s) * 8 + c) * 64 + ln] = acc[s][c];
    } else {
        #pragma unroll
        for (int s = 0; s < SUBT; s++) {
            #pragma unroll
            for (int c = 0; c < 8; c++) {
                float bv = bf2f(cb[c * 16 + lo]);
                #pragma unroll
                for (int r = 0; r < 4; r++) {
                    int pr = pix0 + s * 16 + hi * 4 + r;
                    if (pr < HW)
                        queries[((size_t)l * HW + pr) * CC + c * 16 + lo] =
                            f2bf(acc[s][c][r] + bv);
                }
            }
        }
    }
}

// ---------------------------------------------------------------------------
// Generic MFMA GEMM v3: RT row-tiles/block (B staged once per k-chunk feeds
// RT MFMAs per fragment -> staging traffic / RT). Block: 4 waves,
// RT*64 rows x 128 cols. OMODE: 0 = f32 out, 1 = bf16 out. LN: fused
// LayerNorm over 128-col row (gridDim.x==1, ncols==128).
// ---------------------------------------------------------------------------
template<int OMODE, bool RELU, bool RES, bool LN, int RT>
__global__ __launch_bounds__(256) void gemmm_z(
    const u16* __restrict__ A, const u16* __restrict__ WT, const u16* __restrict__ bias,
    void* __restrict__ outp, const u16* __restrict__ res,
    const u16* __restrict__ lng, const u16* __restrict__ lnb,
    int M, int K, int ldc, int ncols)
{
    __shared__ u16 Blds[128 * 136];
    const int tid = threadIdx.x;
    const int wv = tid >> 6, ln = tid & 63;
    const int lo = ln & 15, hi = ln >> 4;
    const int m0 = blockIdx.y * (RT * 64), n0 = blockIdx.x * 128;

    const u16* arow[RT];
    #pragma unroll
    for (int rt = 0; rt < RT; rt++)
        arow[rt] = A + (size_t)(m0 + (wv * RT + rt) * 16 + lo) * K;

    f32x4v acc[RT][8];
    #pragma unroll
    for (int rt = 0; rt < RT; rt++)
        #pragma unroll
        for (int c = 0; c < 8; c++) acc[rt][c] = (f32x4v){0.f, 0.f, 0.f, 0.f};

    for (int ks = 0; ks < K; ks += 128) {
        __syncthreads();
        {   // stage B^T slab: 128 n-rows x 128 k
            int n = tid >> 1, part = tid & 1;
            const uint4* g = (const uint4*)(WT + (size_t)(n0 + n) * K + ks + part * 64);
            uint4* d = (uint4*)&Blds[n * 136 + part * 64];
            #pragma unroll
            for (int i = 0; i < 8; i++) d[i] = g[i];
        }
        __syncthreads();
        #pragma unroll
        for (int kc = 0; kc < 4; kc++) {
            short8 a[RT];
            #pragma unroll
            for (int rt = 0; rt < RT; rt++)
                a[rt] = *(const short8*)(arow[rt] + ks + kc * 32 + hi * 8);
            #pragma unroll
            for (int c = 0; c < 8; c++) {
                short8 b = *(const short8*)&Blds[(c * 16 + lo) * 136 + kc * 32 + hi * 8];
                #pragma unroll
                for (int rt = 0; rt < RT; rt++)
                    acc[rt][c] = __builtin_amdgcn_mfma_f32_16x16x32_bf16(a[rt], b, acc[rt][c], 0, 0, 0);
            }
        }
    }

    #pragma unroll
    for (int rt = 0; rt < RT; rt++) {
        #pragma unroll
        for (int r = 0; r < 4; r++) {
            int orow = m0 + (wv * RT + rt) * 16 + hi * 4 + r;
            if (orow >= M) continue;         // uniform across the 16-lane shuffle group
            float vv[8];
            #pragma unroll
            for (int c = 0; c < 8; c++) {
                int col = n0 + c * 16 + lo;
                float v = 0.f;
                if (col < ncols) {
                    v = acc[rt][c][r] + bf2f(bias[col]);
                    if (RELU) v = v > 0.f ? v : 0.f;
                    if (RES) v += bf2f(res[(size_t)orow * ldc + col]);
                }
                vv[c] = v;
            }
            if (LN) {
                float s1 = 0.f;
                #pragma unroll
                for (int c = 0; c < 8; c++) s1 += vv[c];
                #pragma unroll
                for (int o = 8; o; o >>= 1) s1 += __shfl_xor(s1, o, 64);
                float mean = s1 * (1.f / 128.f);
                float s2 = 0.f;
                #pragma unroll
                for (int c = 0; c < 8; c++) { float d = vv[c] - mean; s2 += d * d; }
                #pragma unroll
                for (int o = 8; o; o >>= 1) s2 += __shfl_xor(s2, o, 64);
                float rr = rsqrtf(s2 * (1.f / 128.f) + 1e-5f);
                #pragma unroll
                for (int c = 0; c < 8; c++) {
                    int col = n0 + c * 16 + lo;
                    vv[c] = (vv[c] - mean) * rr * bf2f(lng[col]) + bf2f(lnb[col]);
                }
            }
            #pragma unroll
            for (int c = 0; c < 8; c++) {
                int col = n0 + c * 16 + lo;
                if (col >= ncols) continue;
                if (OMODE == 0)
                    ((float*)outp)[(size_t)orow * ldc + col] = vv[c];
                else
                    ((u16*)outp)[(size_t)orow * ldc + col] = f2bf(vv[c]);
            }
        }
    }
}

// ---------------------------------------------------------------------------
// sampling v4 (R12-proven): 16 queries/block, point-split, hoisted gathers.
// ---------------------------------------------------------------------------
__global__ __launch_bounds__(256) void sample3_z(
    const u16* __restrict__ value, const float* __restrict__ proj,
    const float* __restrict__ ref, u16* __restrict__ outp)
{
    const int tid = threadIdx.x;
    const int q = blockIdx.x * 16 + (tid >> 4);
    const int head = tid & 7;
    const int phv = (tid >> 3) & 1;
    if (q >= HW) return;

    float lg[12];
    #pragma unroll
    for (int l = 0; l < 3; l++) {
        float4 v = *(const float4*)(proj + (size_t)(l * HW + q) * 96 + 64 + head * 4);
        lg[l * 4 + 0] = v.x; lg[l * 4 + 1] = v.y; lg[l * 4 + 2] = v.z; lg[l * 4 + 3] = v.w;
    }
    float m = lg[0];
    #pragma unroll
    for (int i = 1; i < 12; i++) m = fmaxf(m, lg[i]);
    float w12[12], sum = 0.f;
    #pragma unroll
    for (int i = 0; i < 12; i++) { w12[i] = __expf(lg[i] - m); sum += w12[i]; }
    float inv = 1.f / sum;

    float acc[16] = {};
    #pragma unroll
    for (int l = 0; l < 3; l++) {
        float rx = ref[(size_t)(q * 3 + l) * 2 + 0] * 180.f - 0.5f;
        float ry = ref[(size_t)(q * 3 + l) * 2 + 1] * 180.f - 0.5f;
        float4 o = *(const float4*)(proj + (size_t)(l * HW + q) * 96 + head * 8 + phv * 4);
        float ox[2] = {o.x, o.z};
        float oy[2] = {o.y, o.w};

        float wqs[8];
        const uint4* vps[8];
        #pragma unroll
        for (int pp = 0; pp < 2; pp++) {
            int p = phv * 2 + pp;
            float px = rx + ox[pp];
            float py = ry + oy[pp];
            float x0f = floorf(px), y0f = floorf(py);
            int x0 = (int)x0f, y0 = (int)y0f;
            float fx = px - x0f, fy = py - y0f;
            float a = w12[l * 4 + p] * inv;
            #pragma unroll
            for (int dy = 0; dy < 2; dy++) {
                int cy = y0 + dy;
                float wy = (dy ? fy : 1.f - fy) * a;
                wy = (cy >= 0 && cy < HDIM) ? wy : 0.f;
                int cyc = min(max(cy, 0), HDIM - 1);
                #pragma unroll
                for (int dx = 0; dx < 2; dx++) {
                    int cx = x0 + dx;
                    float wq = (dx ? fx : 1.f - fx) * wy;
                    wq = (cx >= 0 && cx < HDIM) ? wq : 0.f;
                    int cxc = min(max(cx, 0), HDIM - 1);
                    int c = pp * 4 + dy * 2 + dx;
                    wqs[c] = wq;
                    vps[c] = (const uint4*)(value +
                        (((size_t)l * HW + cyc * HDIM + cxc) * CC + head * 16));
                }
            }
        }
        // issue all 16 loads back-to-back
        uint4 va[8], vb[8];
        #pragma unroll
        for (int c = 0; c < 8; c++) { va[c] = vps[c][0]; vb[c] = vps[c][1]; }
        // accumulate in the original (pp, dy, dx, d) order -> bit-identical
        #pragma unroll
        for (int c = 0; c < 8; c++) {
            float f[8];
            bf8_to_f(va[c], f);
            #pragma unroll
            for (int d = 0; d < 8; d++) acc[d] += wqs[c] * f[d];
            bf8_to_f(vb[c], f);
            #pragma unroll
            for (int d = 0; d < 8; d++) acc[8 + d] += wqs[c] * f[d];
        }
    }
    #pragma unroll
    for (int d = 0; d < 16; d++) acc[d] += __shfl_xor(acc[d], 8, 64);
    if (phv == 0) {
        u16 pack[16];
        #pragma unroll
        for (int d = 0; d < 16; d++) pack[d] = f2bf(acc[d]);
        uint4* op = (uint4*)(outp + (size_t)q * CC + head * 16);
        op[0] = ((uint4*)pack)[0];
        op[1] = ((uint4*)pack)[1];
    }
}

// ---------------------------------------------------------------------------
// FALLBACK (small workspace): fused proj + softmax + sampling (R2-proven).
// ---------------------------------------------------------------------------
__global__ __launch_bounds__(256) void sample_z(
    const u16* __restrict__ value, const u16* __restrict__ queries,
    const u16* __restrict__ woff, const u16* __restrict__ boff,
    const u16* __restrict__ wattn, const u16* __restrict__ battn,
    const float* __restrict__ ref, u16* __restrict__ outp)
{
    __shared__ u16 w_lds[128 * 96];
    __shared__ float bias_lds[96];
    const int tid = threadIdx.x;

    for (int i = tid; i < 128 * 96; i += 256) {
        int k = i / 96, c = i % 96;
        w_lds[i] = (c < 64) ? woff[k * 64 + c] : wattn[k * 32 + (c - 64)];
    }
    if (tid < 96) bias_lds[tid] = bf2f(tid < 64 ? boff[tid] : battn[tid - 64]);
    __syncthreads();

    int q = blockIdx.x * 32 + (tid >> 3);
    int head = tid & 7;
    if (q >= HW) return;

    float og[3][8], lg[12];
    #pragma unroll
    for (int l = 0; l < 3; l++) {
        const u16* qr = queries + ((size_t)l * HW + q) * CC;
        float a12[12] = {};
        #pragma unroll
        for (int kc = 0; kc < 16; kc++) {
            float f[8];
            bf8_to_f(*(const uint4*)(qr + kc * 8), f);
            #pragma unroll
            for (int j = 0; j < 8; j++) {
                const u16* wr = &w_lds[(kc * 8 + j) * 96];
                #pragma unroll
                for (int c = 0; c < 8; c++) a12[c] += f[j] * bf2f(wr[head * 8 + c]);
                #pragma unroll
                for (int c = 0; c < 4; c++) a12[8 + c] += f[j] * bf2f(wr[64 + head * 4 + c]);
            }
        }
        #pragma unroll
        for (int c = 0; c < 8; c++) og[l][c] = a12[c] + bias_lds[head * 8 + c];
        #pragma unroll
        for (int c = 0; c < 4; c++) lg[l * 4 + c] = a12[8 + c] + bias_lds[64 + head * 4 + c];
    }

    float m = lg[0];
    #pragma unroll
    for (int i = 1; i < 12; i++) m = fmaxf(m, lg[i]);
    float w12[12], sum = 0.f;
    #pragma unroll
    for (int i = 0; i < 12; i++) { w12[i] = __expf(lg[i] - m); sum += w12[i]; }
    float inv = 1.f / sum;

    float acc[16] = {};
    #pragma unroll
    for (int l = 0; l < 3; l++) {
        float rx = ref[(size_t)(q * 3 + l) * 2 + 0];
        float ry = ref[(size_t)(q * 3 + l) * 2 + 1];
        #pragma unroll
        for (int p = 0; p < 4; p++) {
            float px = rx * 180.f + og[l][p * 2 + 0] - 0.5f;
            float py = ry * 180.f + og[l][p * 2 + 1] - 0.5f;
            float x0f = floorf(px), y0f = floorf(py);
            int x0 = (int)x0f, y0 = (int)y0f;
            float fx = px - x0f, fy = py - y0f;
            float a = w12[l * 4 + p] * inv;
            #pragma unroll
            for (int dy = 0; dy < 2; dy++) {
                int cy = y0 + dy;
                if (cy < 0 || cy >= HDIM) continue;
                #pragma unroll
                for (int dx = 0; dx < 2; dx++) {
                    int cx = x0 + dx;
                    if (cx < 0 || cx >= HDIM) continue;
                    float wq = a * ((dx ? fx : 1.f - fx) * (dy ? fy : 1.f - fy));
                    const uint4* vp = (const uint4*)(value + (((size_t)l * HW + cy * HDIM + cx) * CC + head * 16));
                    uint4 va = vp[0], vb = vp[1];
                    float f[8];
                    bf8_to_f(va, f);
                    #pragma unroll
                    for (int d = 0; d < 8; d++) acc[d] += wq * f[d];
                    bf8_to_f(vb, f);
                    #pragma unroll
                    for (int d = 0; d < 8; d++) acc[8 + d] += wq * f[d];
                }
            }
        }
    }
    u16 pack[16];
    #pragma unroll
    for (int d = 0; d < 16; d++) pack[d] = f2bf(acc[d]);
    uint4* op = (uint4*)(outp + (size_t)q * CC + head * 16);
    op[0] = ((uint4*)pack)[0];
    op[1] = ((uint4*)pack)[1];
}

// LayerNorm in place, bf16 buffer (fallback path)
__global__ __launch_bounds__(256) void ln_z(
    u16* __restrict__ x, const u16* __restrict__ g, const u16* __restrict__ b, int M)
{
    int row = blockIdx.x * 4 + (threadIdx.x >> 6);
    int lane = threadIdx.x & 63;
    if (row >= M) return;
    u16* xr = x + (size_t)row * 128;
    float v0 = bf2f(xr[lane]), v1 = bf2f(xr[lane + 64]);
    float s = v0 + v1;
    #pragma unroll
    for (int o = 32; o; o >>= 1) s += __shfl_xor(s, o, 64);
    float mean = s * (1.f / 128.f);
    float d0 = v0 - mean, d1 = v1 - mean;
    float vs = d0 * d0 + d1 * d1;
    #pragma unroll
    for (int o = 32; o; o >>= 1) vs += __shfl_xor(vs, o, 64);
    float r = rsqrtf(vs * (1.f / 128.f) + 1e-5f);
    xr[lane]      = f2bf(d0 * r * bf2f(g[lane])      + bf2f(b[lane]));
    xr[lane + 64] = f2bf(d1 * r * bf2f(g[lane + 64]) + bf2f(b[lane + 64]));
}

// LayerNorm in place, FLOAT32 buffer (fallback path)
__global__ __launch_bounds__(256) void ln32_z(
    float* __restrict__ x, const u16* __restrict__ g, const u16* __restrict__ b, int M)
{
    int row = blockIdx.x * 4 + (threadIdx.x >> 6);
    int lane = threadIdx.x & 63;
    if (row >= M) return;
    float* xr = x + (size_t)row * 128;
    float v0 = xr[lane], v1 = xr[lane + 64];
    float s = v0 + v1;
    #pragma unroll
    for (int o = 32; o; o >>= 1) s += __shfl_xor(s, o, 64);
    float mean = s * (1.f / 128.f);
    float d0 = v0 - mean, d1 = v1 - mean;
    float vs = d0 * d0 + d1 * d1;
    #pragma unroll
    for (int o = 32; o; o >>= 1) vs += __shfl_xor(vs, o, 64);
    float r = rsqrtf(vs * (1.f / 128.f) + 1e-5f);
    xr[lane]      = d0 * r * bf2f(g[lane])      + bf2f(b[lane]);
    xr[lane + 64] = d1 * r * bf2f(g[lane + 64]) + bf2f(b[lane + 64]);
}

extern "C" void kernel_launch(void* const* d_in, const int* in_sizes, int n_in,
                              void* d_out, int out_size, void* d_ws, size_t ws_size,
                              hipStream_t stream)
{
    char* ws = (char*)d_ws;
    u16* canon   = (u16*)ws;                      // 26,480,512 B
    u16* value   = (u16*)(ws + 26480512);         // 24,883,200 B
    u16* queries = (u16*)(ws + 51363712);         // 24,883,200 B
    u16* src     = (u16*)(ws + 26480512);         // aliases dead value (8.3 MB)
    float* dout  = (float*)d_out;                 // FLOAT32 output

    const size_t PROJ_OFF = 76246912;
    const size_t PROJ_END = PROJ_OFF + (size_t)3 * HW * 96 * 4;   // 113,571,712
    const bool big = ws_size >= PROJ_END;
    float* proj  = (float*)(ws + PROJ_OFF);
    u16* wtbuf   = (u16*)(ws + PROJ_OFF);         // conv wt (590 KB), dead before proj
    f32x4v* q0   = (f32x4v*)(ws + PROJ_OFF + 1048576);  // ~16.7 MB, inside proj region
    u16* out_s   = big ? (u16*)(ws + 51363712) : (u16*)(ws + 76246912);
    u16* hidden  = (u16*)(ws + 51363712);         // FFN hidden, 33.2 MB/stripe (2 stripes)

    // MFMA-GEMM transposed weights:
    u16* WvalT = (u16*)(ws + 51363712);           // queries region, pre-conv (32 KB)
    u16* W1T   = (u16*)(ws + 34774912);           // value tail after src (256 KB)
    u16* W2T   = (u16*)(ws + 35037056);           // value tail (256 KB)
    u16* wcatT = (u16*)d_out;                     // d_out scratch, dead until FFN2
    u16* b128  = (u16*)d_out + 16384;
    u16* WoutT = (u16*)d_out + 32768;             // d_out scratch (32 KB)

    // locate weight base: conv_w has unique element count 294912
    int i_cw = 2;
    while (i_cw < n_in - 17 && in_sizes[i_cw] != 294912) i_cw++;
    if (i_cw >= n_in - 17) i_cw = 3;

    PtrsZ ptrs;
    ptrs.p[0] = d_in[0];                // src_all
    ptrs.p[1] = d_in[1];                // reference_points
    for (int i = 0; i < 18; i++) ptrs.p[2 + i] = d_in[i_cw + i];

    const u16* csrc  = canon + CAN_SRC;
    const u16* ccw   = canon + CAN_CW;
    const u16* ccb   = canon + CAN_CB;
    const u16* cWval = canon + CAN_WVAL,  *cbval = canon + CAN_BVAL;
    const u16* cWoff = canon + CAN_WOFF,  *cboff = canon + CAN_BOFF;
    const u16* cWatt = canon + CAN_WATTN, *cbatt = canon + CAN_BATTN;
    const u16* cWout = canon + CAN_WOUT,  *cbout = canon + CAN_BOUT;
    const u16* cg1   = canon + CAN_LN1G,  *cb1n  = canon + CAN_LN1B;
    const u16* cW1   = canon + CAN_W1,    *cbf1  = canon + CAN_B1;
    const u16* cW2   = canon + CAN_W2,    *cbf2  = canon + CAN_B2;
    const u16* cg2   = canon + CAN_LN2G,  *cb2n  = canon + CAN_LN2B;

    convert_z<<<dim3((CAN_TOTAL + 255) / 256), 256, 0, stream>>>(ptrs, canon);

    const int M3 = 3 * HW, M1 = HW;

    if (big) {
        // prep: conv-wt + WvalT + Wcat/b128 + WoutT (one launch)
        prep1_z<<<dim3((344192 + 255) / 256), 256, 0, stream>>>(
            ccw, cWval, cWout, cWoff, cWatt, cboff, cbatt,
            wtbuf, WvalT, wcatT, b128, WoutT);
        // 1. value = src_all @ W_val + b_val  (RT=3: stage B once per 192 rows)
        gemmm_z<1, false, false, false, 3><<<dim3(1, 507), 256, 0, stream>>>(
            csrc, WvalT, cbval, value, nullptr, nullptr, nullptr, M3, 128, 128, 128);
        // 2. conv -> queries, half-factored:
        //    2a. frame-0 half once (SUBT=2, grid 254 balanced) -> q0
        convh_z<0, 2><<<dim3((HW + 127) / 128, 1), 256, 0, stream>>>(
            csrc, wtbuf, ccb, q0, queries);
        //    2b. per-l half (SUBT=3, grid 507 ~ 2/CU) -> queries
        convh_z<1, 3><<<dim3((HW + 191) / 192, 3), 256, 0, stream>>>(
            csrc, wtbuf, ccb, q0, queries);
        // 3a. proj[M3][96] = queries @ WcatT + bias128  (RT=3)
        gemmm_z<0, false, false, false, 3><<<dim3(1, 507), 256, 0, stream>>>(
            queries, wcatT, b128, proj, nullptr, nullptr, nullptr, M3, 128, 96, 96);
        // 3b. sampling (hoisted gathers) -> out_s
        sample3_z<<<dim3((HW + 15) / 16), 256, 0, stream>>>(
            value, proj, (const float*)d_in[1], out_s);
        // value now dead -> W1T/W2T in its tail
        w12t_z<<<dim3(1024), 256, 0, stream>>>(cW1, cW2, W1T, W2T);
        // 4. src = LN1(out_s @ W_out + b_out + src_all[0])  [LN fused, RT=1]
        gemmm_z<1, false, true, true, 1><<<dim3(1, 507), 256, 0, stream>>>(
            out_s, WoutT, cbout, src, csrc, cg1, cb1n, M1, 128, 128, 128);
        // 5-6. FFN in 2 stripes; FFN1 RT=2; FFN2 RT=1 fuses residual + LN2
        for (int sblk = 0; sblk < 2; sblk++) {
            const u16* srow = src + (size_t)sblk * 16200 * 128;
            float* drow = dout + (size_t)sblk * 16200 * 128;
            gemmm_z<1, true, false, false, 2><<<dim3(8, 127), 256, 0, stream>>>(
                srow, W1T, cbf1, hidden, nullptr, nullptr, nullptr, 16200, 128, 1024, 1024);
            gemmm_z<0, false, true, true, 1><<<dim3(1, 254), 256, 0, stream>>>(
                hidden, W2T, cbf2, drow, srow, cg2, cb2n, 16200, 1024, 128, 128);
        }
    } else {
        // --- fallback: R2-proven VALU path ---
        u16* out_f = (u16*)(ws + 76246912);
        u16* hid_f = (u16*)(ws + 51363712);
        gemm_z<true, false, false><<<dim3(2, 1519), 256, 0, stream>>>(
            csrc, cWval, cbval, value, nullptr, M3, 128, 128);
        conv_z<<<dim3(9, 45, 3), 256, 0, stream>>>(csrc, ccw, ccb, queries);
        sample_z<<<dim3(1013), 256, 0, stream>>>(
            value, queries, cWoff, cboff, cWatt, cbatt, (const float*)d_in[1], out_f);
        gemm_z<true, false, true><<<dim3(2, 507), 256, 0, stream>>>(
            out_f, cWout, cbout, src, csrc, M1, 128, 128);
        ln_z<<<dim3(8100), 256, 0, stream>>>(src, cg1, cb1n, M1);
        for (int sblk = 0; sblk < 4; sblk++) {
            const u16* srow = src + (size_t)sblk * 8100 * 128;
            float* drow = dout + (size_t)sblk * 8100 * 128;
            gemm_z<true, true, false><<<dim3(16, 127), 256, 0, stream>>>(
                srow, cW1, cbf1, hid_f, nullptr, 8100, 1024, 128);
            gemm_z<false, false, true><<<dim3(2, 127), 256, 0, stream>>>(
                hid_f, cW2, cbf2, drow, srow, 8100, 128, 1024);
        }
        ln32_z<<<dim3(8100), 256, 0, stream>>>(dout, cg2, cb2n, M1);
    }
}

// Round 15
// 489.091 us; speedup vs baseline: 1.0747x; 1.0747x over previous
//
#include <hip/hip_runtime.h>

typedef unsigned short u16;
typedef unsigned int u32;

#define HDIM 180
#define HW 32400
#define CC 128

// canon element offsets (bf16), same map as proven R2 build
#define CAN_SRC   0
#define CAN_REF   12441600
#define CAN_CW    12636000
#define CAN_CB    12930912
#define CAN_WVAL  12931040
#define CAN_BVAL  12947424
#define CAN_WOFF  12947552
#define CAN_BOFF  12955744
#define CAN_WATTN 12955808
#define CAN_BATTN 12959904
#define CAN_WOUT  12959936
#define CAN_BOUT  12976320
#define CAN_LN1G  12976448
#define CAN_LN1B  12976576
#define CAN_W1    12976704
#define CAN_B1    13107776
#define CAN_W2    13108800
#define CAN_B2    13239872
#define CAN_LN2G  13240000
#define CAN_LN2B  13240128
#define CAN_TOTAL 13240256

typedef short short8 __attribute__((ext_vector_type(8)));
typedef float f32x4v __attribute__((ext_vector_type(4)));

__device__ __forceinline__ float bf2f(u16 v) { return __uint_as_float(((u32)v) << 16); }
__device__ __forceinline__ u16 f2bf(float f) {
    u32 x = __float_as_uint(f);
    return (u16)((x + 0x7FFFu + ((x >> 16) & 1u)) >> 16);
}
__device__ __forceinline__ void bf8_to_f(const uint4 v, float* o) {
    o[0] = __uint_as_float(v.x << 16); o[1] = __uint_as_float(v.x & 0xFFFF0000u);
    o[2] = __uint_as_float(v.y << 16); o[3] = __uint_as_float(v.y & 0xFFFF0000u);
    o[4] = __uint_as_float(v.z << 16); o[5] = __uint_as_float(v.z & 0xFFFF0000u);
    o[6] = __uint_as_float(v.w << 16); o[7] = __uint_as_float(v.w & 0xFFFF0000u);
}

// ---------------------------------------------------------------------------
// Canonicalize src/ref/weights to bf16.
// ---------------------------------------------------------------------------
struct PtrsZ { const void* p[20]; };

__global__ __launch_bounds__(256) void convert_z(PtrsZ ptrs, u16* __restrict__ out)
{
    const int offs[20] = {CAN_SRC, CAN_REF, CAN_CW, CAN_CB, CAN_WVAL, CAN_BVAL,
                          CAN_WOFF, CAN_BOFF, CAN_WATTN, CAN_BATTN, CAN_WOUT, CAN_BOUT,
                          CAN_LN1G, CAN_LN1B, CAN_W1, CAN_B1, CAN_W2, CAN_B2,
                          CAN_LN2G, CAN_LN2B};
    int gid = blockIdx.x * 256 + threadIdx.x;
    if (gid >= CAN_TOTAL) return;
    int t = 0;
    #pragma unroll
    for (int i = 1; i < 20; i++) t += (gid >= offs[i]) ? 1 : 0;
    int e = gid - offs[t];
    bool isb = (*(const u32*)ptrs.p[12]) == 0x3F803F80u;   // ln1_g
    out[gid] = isb ? ((const u16*)ptrs.p[t])[e] : f2bf(((const float*)ptrs.p[t])[e]);
}

// ---------------------------------------------------------------------------
// Merged prep: conv-wt transpose + WvalT + Wcat/b128 + WoutT (one launch).
// ---------------------------------------------------------------------------
__global__ __launch_bounds__(256) void prep1_z(
    const u16* __restrict__ cw, const u16* __restrict__ wval, const u16* __restrict__ wout,
    const u16* __restrict__ woff, const u16* __restrict__ wattn,
    const u16* __restrict__ boff, const u16* __restrict__ battn,
    u16* __restrict__ wtbuf, u16* __restrict__ wvalT,
    u16* __restrict__ wcat, u16* __restrict__ b128, u16* __restrict__ woutT)
{
    int gid = blockIdx.x * 256 + threadIdx.x;
    if (gid < 294912) {                       // conv wt[half][tap][co][ci]
        int ci = gid & 127, co = (gid >> 7) & 127, rest = gid >> 14;
        int tap = rest % 9, half = rest / 9;
        wtbuf[gid] = cw[(size_t)co * 2304 + (half * 128 + ci) * 9 + tap];
    } else if (gid < 311296) {                // WvalT[n][k]
        int e = gid - 294912;
        int k = e >> 7, n = e & 127;
        wvalT[n * 128 + k] = wval[e];
    } else if (gid < 327808) {                // WcatT + b128
        int e = gid - 311296;
        if (e < 16384) {
            int n = e >> 7, k = e & 127;
            u16 v = 0;
            if (n < 64) v = woff[k * 64 + n];
            else if (n < 96) v = wattn[k * 32 + (n - 64)];
            wcat[n * 128 + k] = v;
        } else {
            int n = e - 16384;
            u16 v = 0;
            if (n < 64) v = boff[n]; else if (n < 96) v = battn[n - 64];
            b128[n] = v;
        }
    } else if (gid < 344192) {                // WoutT[n][k]
        int e = gid - 327808;
        int k = e >> 7, n = e & 127;
        woutT[n * 128 + k] = wout[e];
    }
}

// W1T/W2T (after value is dead)
__global__ __launch_bounds__(256) void w12t_z(
    const u16* __restrict__ w1, const u16* __restrict__ w2,
    u16* __restrict__ w1t, u16* __restrict__ w2t)
{
    int gid = blockIdx.x * 256 + threadIdx.x;
    if (gid < 131072) {                       // W1 [128][1024]
        int k = gid >> 10, n = gid & 1023;
        w1t[(size_t)n * 128 + k] = w1[gid];
    } else if (gid < 262144) {                // W2 [1024][128]
        int e = gid - 131072;
        int k = e >> 7, n = e & 127;
        w2t[(size_t)n * 1024 + k] = w2[e];
    }
}

// ---------------------------------------------------------------------------
// FALLBACK tiled VALU GEMM (small-ws path only).
// ---------------------------------------------------------------------------
template<bool OUT_BF16, bool RELU, bool RES>
__global__ __launch_bounds__(256) void gemm_z(
    const u16* __restrict__ A, const u16* __restrict__ W, const u16* __restrict__ bias,
    void* __restrict__ outp, const u16* __restrict__ res, int M, int N, int K)
{
    __shared__ float As[64][68];
    __shared__ float Bs[64][68];
    const int tid = threadIdx.x;
    const int tx = tid & 15, ty = tid >> 4;
    const int m0 = blockIdx.y * 64, n0 = blockIdx.x * 64;
    float acc[4][4] = {};

    for (int k0 = 0; k0 < K; k0 += 64) {
        __syncthreads();
        #pragma unroll
        for (int i = tid; i < 512; i += 256) {
            int row = i >> 3, part = i & 7;
            float f[8];
            if (m0 + row < M) {
                uint4 v = *(const uint4*)(A + (size_t)(m0 + row) * K + k0 + part * 8);
                bf8_to_f(v, f);
            } else {
                #pragma unroll
                for (int j = 0; j < 8; j++) f[j] = 0.f;
            }
            #pragma unroll
            for (int j = 0; j < 8; j++) As[part * 8 + j][row] = f[j];
        }
        #pragma unroll
        for (int i = tid; i < 512; i += 256) {
            int kr = i >> 3, np = i & 7;
            float f[8];
            uint4 v = *(const uint4*)(W + (size_t)(k0 + kr) * N + n0 + np * 8);
            bf8_to_f(v, f);
            #pragma unroll
            for (int j = 0; j < 8; j++) Bs[kr][np * 8 + j] = f[j];
        }
        __syncthreads();
        #pragma unroll 8
        for (int kk = 0; kk < 64; kk++) {
            float4 a = *(const float4*)&As[kk][ty * 4];
            float4 b = *(const float4*)&Bs[kk][tx * 4];
            float av[4] = {a.x, a.y, a.z, a.w};
            float bv[4] = {b.x, b.y, b.z, b.w};
            #pragma unroll
            for (int i = 0; i < 4; i++)
                #pragma unroll
                for (int j = 0; j < 4; j++)
                    acc[i][j] += av[i] * bv[j];
        }
    }

    #pragma unroll
    for (int i = 0; i < 4; i++) {
        int row = m0 + ty * 4 + i;
        if (row >= M) continue;
        #pragma unroll
        for (int j = 0; j < 4; j++) {
            int col = n0 + tx * 4 + j;
            float v = acc[i][j] + bf2f(bias[col]);
            if (RELU) v = v > 0.f ? v : 0.f;
            if (RES) v += bf2f(res[(size_t)row * N + col]);
            if (OUT_BF16) ((u16*)outp)[(size_t)row * N + col] = f2bf(v);
            else          ((float*)outp)[(size_t)row * N + col] = v;
        }
    }
}

// ---------------------------------------------------------------------------
// FALLBACK (small ws): 3x3 SAME conv, f32 VALU version (R2-proven).
// ---------------------------------------------------------------------------
__global__ __launch_bounds__(256) void conv_z(
    const u16* __restrict__ src, const u16* __restrict__ cw, const u16* __restrict__ cb,
    u16* __restrict__ queries)
{
    __shared__ float in_lds[8 * 6 * 22];
    __shared__ float w_lds[8 * 9 * 128];
    const int tid = threadIdx.x;
    const int wt = blockIdx.x, ht = blockIdx.y, l = blockIdx.z;
    const int h0 = ht * 4, w0 = wt * 20;
    const int cog = tid & 15, pxg = tid >> 4;
    const int pr = pxg >> 2, c0 = (pxg & 3) * 5;

    float acc[5][8] = {};

    for (int ch = 0; ch < 32; ch++) {
        const int ci0 = ch * 8;
        const int fsel = (ci0 < 128) ? 0 : l;
        const int cbase = ci0 & 127;
        __syncthreads();
        if (tid < 132) {
            int r = tid / 22, c = tid % 22;
            int gh = h0 - 1 + r, gw = w0 - 1 + c;
            float f[8];
            if (gh >= 0 && gh < HDIM && gw >= 0 && gw < HDIM) {
                uint4 v = *(const uint4*)(src + ((size_t)fsel * HW + gh * HDIM + gw) * CC + cbase);
                bf8_to_f(v, f);
            } else {
                #pragma unroll
                for (int j = 0; j < 8; j++) f[j] = 0.f;
            }
            #pragma unroll
            for (int j = 0; j < 8; j++) in_lds[j * 132 + r * 22 + c] = f[j];
        }
        for (int i = tid; i < 1152; i += 256) {
            int co = i & 127, part = i >> 7;
            uint4 v = *(const uint4*)(cw + (size_t)co * 2304 + ci0 * 9 + part * 8);
            float f[8]; bf8_to_f(v, f);
            #pragma unroll
            for (int j = 0; j < 8; j++) {
                int flat = part * 8 + j;
                int ci = flat / 9, k = flat % 9;
                w_lds[ci * 1152 + k * 128 + co] = f[j];
            }
        }
        __syncthreads();

        #pragma unroll
        for (int ci = 0; ci < 8; ci++) {
            float xv[3][7];
            #pragma unroll
            for (int r = 0; r < 3; r++)
                #pragma unroll
                for (int c = 0; c < 7; c++)
                    xv[r][c] = in_lds[ci * 132 + (pr + r) * 22 + (c0 + c)];
            const float* wbase = &w_lds[ci * 1152];
            #pragma unroll
            for (int j8 = 0; j8 < 8; j8++) {
                int co = cog + 16 * j8;
                float w_[9];
                #pragma unroll
                for (int k = 0; k < 9; k++) w_[k] = wbase[k * 128 + co];
                #pragma unroll
                for (int j = 0; j < 5; j++) {
                    acc[j][j8] += xv[0][j] * w_[0] + xv[0][j + 1] * w_[1] + xv[0][j + 2] * w_[2]
                                + xv[1][j] * w_[3] + xv[1][j + 1] * w_[4] + xv[1][j + 2] * w_[5]
                                + xv[2][j] * w_[6] + xv[2][j + 1] * w_[7] + xv[2][j + 2] * w_[8];
                }
            }
        }
    }

    float bias[8];
    #pragma unroll
    for (int j8 = 0; j8 < 8; j8++) bias[j8] = bf2f(cb[cog + 16 * j8]);
    #pragma unroll
    for (int j = 0; j < 5; j++) {
        int q = (h0 + pr) * HDIM + (w0 + c0 + j);
        u16* qp = queries + ((size_t)l * HW + q) * CC;
        #pragma unroll
        for (int j8 = 0; j8 < 8; j8++)
            qp[cog + 16 * j8] = f2bf(acc[j][j8] + bias[j8]);
    }
}

// ---------------------------------------------------------------------------
// conv half-0 (frame 0, l-independent), computed ONCE: 128 px/block,
// 2 sub-tiles/wave, grid 254 (R12-measured). Partial acc -> q0 in global
// fragment-block order (pb = pixel/16).
// ---------------------------------------------------------------------------
__global__ __launch_bounds__(256) void convh0_z(
    const u16* __restrict__ src, const u16* __restrict__ wt,
    f32x4v* __restrict__ q0)
{
    __shared__ uint4 Blds[2][2048];   // 64 KB, double-buffered
    const int tid = threadIdx.x;
    const int wv = tid >> 6, ln = tid & 63;
    const int lo = ln & 15, hi = ln >> 4;
    const int pix0 = blockIdx.x * 128 + wv * 32;
    const int pb0 = blockIdx.x * 8 + wv * 2;

    int ph[2], pc[2];
    #pragma unroll
    for (int s = 0; s < 2; s++) {
        int p = pix0 + s * 16 + lo;
        ph[s] = p / HDIM; pc[s] = p % HDIM;
    }

    f32x4v acc[2][8];
    #pragma unroll
    for (int s = 0; s < 2; s++)
        #pragma unroll
        for (int c = 0; c < 8; c++) acc[s][c] = (f32x4v){0.f, 0.f, 0.f, 0.f};

    const int sco = tid >> 1, spart = tid & 1;
    const int sc8 = sco >> 4, slo = sco & 15;

    {
        const uint4* g = (const uint4*)(wt + (size_t)sco * 128 + spart * 64);
        uint4 gr[8];
        #pragma unroll
        for (int i = 0; i < 8; i++) gr[i] = g[i];
        #pragma unroll
        for (int i = 0; i < 8; i++) {
            int k8 = spart * 8 + i;
            Blds[0][((k8 >> 2) * 8 + sc8) * 64 + (k8 & 3) * 16 + slo] = gr[i];
        }
    }
    __syncthreads();

    for (int t = 0; t < 9; t++) {
        const int cur = t & 1;
        uint4 gr[8];
        if (t < 8) {
            const uint4* g = (const uint4*)(wt + (size_t)(t + 1) * 16384 +
                                            (size_t)sco * 128 + spart * 64);
            #pragma unroll
            for (int i = 0; i < 8; i++) gr[i] = g[i];
        }

        const int dy = t / 3 - 1, dx = t % 3 - 1;
        const int sh0 = ph[0] + dy, sc0 = pc[0] + dx;
        const int sh1 = ph[1] + dy, sc1 = pc[1] + dx;
        const bool v0 = (sh0 >= 0) && (sh0 < HDIM) && (sc0 >= 0) && (sc0 < HDIM);
        const bool v1 = (sh1 >= 0) && (sh1 < HDIM) && (sc1 >= 0) && (sc1 < HDIM);
        const u16* arow0 = src + (size_t)(sh0 * HDIM + sc0) * CC;
        const u16* arow1 = src + (size_t)(sh1 * HDIM + sc1) * CC;

        #pragma unroll
        for (int kc = 0; kc < 4; kc++) {
            short8 a0 = {}, a1 = {};
            if (v0) a0 = *(const short8*)(arow0 + kc * 32 + hi * 8);
            if (v1) a1 = *(const short8*)(arow1 + kc * 32 + hi * 8);
            #pragma unroll
            for (int c = 0; c < 8; c++) {
                short8 b = ((const short8*)&Blds[cur][0])[(kc * 8 + c) * 64 + ln];
                acc[0][c] = __builtin_amdgcn_mfma_f32_16x16x32_bf16(a0, b, acc[0][c], 0, 0, 0);
                acc[1][c] = __builtin_amdgcn_mfma_f32_16x16x32_bf16(a1, b, acc[1][c], 0, 0, 0);
            }
        }

        if (t < 8) {
            #pragma unroll
            for (int i = 0; i < 8; i++) {
                int k8 = spart * 8 + i;
                Blds[cur ^ 1][((k8 >> 2) * 8 + sc8) * 64 + (k8 & 3) * 16 + slo] = gr[i];
            }
        }
        __syncthreads();
    }

    #pragma unroll
    for (int s = 0; s < 2; s++)
        #pragma unroll
        for (int c = 0; c < 8; c++)
            q0[((size_t)(pb0 + s) * 8 + c) * 64 + ln] = acc[s][c];
}

// ---------------------------------------------------------------------------
// conv half-1 (per-l frame): 192 px/block, 3 sub-tiles/wave (named vars —
// R13-measured 81 us, no scratch), grid 507 ~ 2/CU. acc init from q0;
// + bias -> queries.
// ---------------------------------------------------------------------------
__global__ __launch_bounds__(256) void convh1_z(
    const u16* __restrict__ src, const u16* __restrict__ wt, const u16* __restrict__ cb,
    const f32x4v* __restrict__ q0, u16* __restrict__ queries)
{
    __shared__ uint4 Blds[2][2048];   // 64 KB, double-buffered
    const int tid = threadIdx.x;
    const int wv = tid >> 6, ln = tid & 63;
    const int lo = ln & 15, hi = ln >> 4;
    const int l = blockIdx.y;
    const int pix0 = blockIdx.x * 192 + wv * 48;
    const int pb0 = blockIdx.x * 12 + wv * 3;

    int ph[3], pc[3];
    #pragma unroll
    for (int s = 0; s < 3; s++) {
        int p = pix0 + s * 16 + lo;
        ph[s] = p / HDIM; pc[s] = p % HDIM;
    }

    f32x4v acc[3][8];
    #pragma unroll
    for (int s = 0; s < 3; s++)
        #pragma unroll
        for (int c = 0; c < 8; c++)
            acc[s][c] = q0[((size_t)(pb0 + s) * 8 + c) * 64 + ln];

    const u16* wthalf = wt + (size_t)9 * 16384;
    const u16* sbase  = src + (size_t)l * HW * CC;

    const int sco = tid >> 1, spart = tid & 1;
    const int sc8 = sco >> 4, slo = sco & 15;

    {
        const uint4* g = (const uint4*)(wthalf + (size_t)sco * 128 + spart * 64);
        uint4 gr[8];
        #pragma unroll
        for (int i = 0; i < 8; i++) gr[i] = g[i];
        #pragma unroll
        for (int i = 0; i < 8; i++) {
            int k8 = spart * 8 + i;
            Blds[0][((k8 >> 2) * 8 + sc8) * 64 + (k8 & 3) * 16 + slo] = gr[i];
        }
    }
    __syncthreads();

    for (int t = 0; t < 9; t++) {
        const int cur = t & 1;
        uint4 gr[8];
        if (t < 8) {
            const uint4* g = (const uint4*)(wthalf + (size_t)(t + 1) * 16384 +
                                            (size_t)sco * 128 + spart * 64);
            #pragma unroll
            for (int i = 0; i < 8; i++) gr[i] = g[i];
        }

        const int dy = t / 3 - 1, dx = t % 3 - 1;
        int sh[3], scx[3];
        bool vld[3];
        const u16* arow[3];
        #pragma unroll
        for (int s = 0; s < 3; s++) {
            sh[s] = ph[s] + dy; scx[s] = pc[s] + dx;
            vld[s] = (sh[s] >= 0) && (sh[s] < HDIM) && (scx[s] >= 0) && (scx[s] < HDIM);
            arow[s] = sbase + (size_t)(sh[s] * HDIM + scx[s]) * CC;
        }

        #pragma unroll
        for (int kc = 0; kc < 4; kc++) {
            short8 a0 = {}, a1 = {}, a2 = {};
            if (vld[0]) a0 = *(const short8*)(arow[0] + kc * 32 + hi * 8);
            if (vld[1]) a1 = *(const short8*)(arow[1] + kc * 32 + hi * 8);
            if (vld[2]) a2 = *(const short8*)(arow[2] + kc * 32 + hi * 8);
            #pragma unroll
            for (int c = 0; c < 8; c++) {
                short8 b = ((const short8*)&Blds[cur][0])[(kc * 8 + c) * 64 + ln];
                acc[0][c] = __builtin_amdgcn_mfma_f32_16x16x32_bf16(a0, b, acc[0][c], 0, 0, 0);
                acc[1][c] = __builtin_amdgcn_mfma_f32_16x16x32_bf16(a1, b, acc[1][c], 0, 0, 0);
                acc[2][c] = __builtin_amdgcn_mfma_f32_16x16x32_bf16(a2, b, acc[2][c], 0, 0, 0);
            }
        }

        if (t < 8) {
            #pragma unroll
            for (int i = 0; i < 8; i++) {
                int k8 = spart * 8 + i;
                Blds[cur ^ 1][((k8 >> 2) * 8 + sc8) * 64 + (k8 & 3) * 16 + slo] = gr[i];
            }
        }
        __syncthreads();
    }

    #pragma unroll
    for (int s = 0; s < 3; s++) {
        #pragma unroll
        for (int c = 0; c < 8; c++) {
            float bv = bf2f(cb[c * 16 + lo]);
            #pragma unroll
            for (int r = 0; r < 4; r++) {
                int pr = pix0 + s * 16 + hi * 4 + r;
                if (pr < HW)
                    queries[((size_t)l * HW + pr) * CC + c * 16 + lo] =
                        f2bf(acc[s][c][r] + bv);
            }
        }
    }
}

// ---------------------------------------------------------------------------
// Generic MFMA GEMM (R12-proven). out[M,ncols] = A[M,K] @ WT[N,K]^T + bias
// (+res)(relu?). Block: 4 waves, 64 rows x 128 cols.
// OMODE: 0 = f32 out, 1 = bf16 out. LN: fused LayerNorm (gridDim.x==1).
// ---------------------------------------------------------------------------
template<int OMODE, bool RELU, bool RES, bool LN>
__global__ __launch_bounds__(256) void gemmm_z(
    const u16* __restrict__ A, const u16* __restrict__ WT, const u16* __restrict__ bias,
    void* __restrict__ outp, const u16* __restrict__ res,
    const u16* __restrict__ lng, const u16* __restrict__ lnb,
    int M, int K, int ldc, int ncols)
{
    __shared__ u16 Blds[128 * 136];
    const int tid = threadIdx.x;
    const int wv = tid >> 6, ln = tid & 63;
    const int lo = ln & 15, hi = ln >> 4;
    const int m0 = blockIdx.y * 64, n0 = blockIdx.x * 128;
    const int row = m0 + wv * 16 + lo;
    const u16* arow = A + (size_t)row * K;

    f32x4v acc[8] = {};

    for (int ks = 0; ks < K; ks += 128) {
        __syncthreads();
        {   // stage B^T slab: 128 n-rows x 128 k
            int n = tid >> 1, part = tid & 1;
            const uint4* g = (const uint4*)(WT + (size_t)(n0 + n) * K + ks + part * 64);
            uint4* d = (uint4*)&Blds[n * 136 + part * 64];
            #pragma unroll
            for (int i = 0; i < 8; i++) d[i] = g[i];
        }
        __syncthreads();
        #pragma unroll
        for (int kc = 0; kc < 4; kc++) {
            short8 a = *(const short8*)(arow + ks + kc * 32 + hi * 8);
            #pragma unroll
            for (int c = 0; c < 8; c++) {
                short8 b = *(const short8*)&Blds[(c * 16 + lo) * 136 + kc * 32 + hi * 8];
                acc[c] = __builtin_amdgcn_mfma_f32_16x16x32_bf16(a, b, acc[c], 0, 0, 0);
            }
        }
    }

    #pragma unroll
    for (int r = 0; r < 4; r++) {
        int orow = m0 + wv * 16 + hi * 4 + r;
        if (orow >= M) continue;             // uniform across the 16-lane shuffle group
        float vv[8];
        #pragma unroll
        for (int c = 0; c < 8; c++) {
            int col = n0 + c * 16 + lo;
            float v = 0.f;
            if (col < ncols) {
                v = acc[c][r] + bf2f(bias[col]);
                if (RELU) v = v > 0.f ? v : 0.f;
                if (RES) v += bf2f(res[(size_t)orow * ldc + col]);
            }
            vv[c] = v;
        }
        if (LN) {
            float s1 = 0.f;
            #pragma unroll
            for (int c = 0; c < 8; c++) s1 += vv[c];
            #pragma unroll
            for (int o = 8; o; o >>= 1) s1 += __shfl_xor(s1, o, 64);
            float mean = s1 * (1.f / 128.f);
            float s2 = 0.f;
            #pragma unroll
            for (int c = 0; c < 8; c++) { float d = vv[c] - mean; s2 += d * d; }
            #pragma unroll
            for (int o = 8; o; o >>= 1) s2 += __shfl_xor(s2, o, 64);
            float rr = rsqrtf(s2 * (1.f / 128.f) + 1e-5f);
            #pragma unroll
            for (int c = 0; c < 8; c++) {
                int col = n0 + c * 16 + lo;
                vv[c] = (vv[c] - mean) * rr * bf2f(lng[col]) + bf2f(lnb[col]);
            }
        }
        #pragma unroll
        for (int c = 0; c < 8; c++) {
            int col = n0 + c * 16 + lo;
            if (col >= ncols) continue;
            if (OMODE == 0)
                ((float*)outp)[(size_t)orow * ldc + col] = vv[c];
            else
                ((u16*)outp)[(size_t)orow * ldc + col] = f2bf(vv[c]);
        }
    }
}

// ---------------------------------------------------------------------------
// sampling v4 (R12-proven): 16 queries/block, point-split, hoisted gathers.
// ---------------------------------------------------------------------------
__global__ __launch_bounds__(256) void sample3_z(
    const u16* __restrict__ value, const float* __restrict__ proj,
    const float* __restrict__ ref, u16* __restrict__ outp)
{
    const int tid = threadIdx.x;
    const int q = blockIdx.x * 16 + (tid >> 4);
    const int head = tid & 7;
    const int phv = (tid >> 3) & 1;
    if (q >= HW) return;

    float lg[12];
    #pragma unroll
    for (int l = 0; l < 3; l++) {
        float4 v = *(const float4*)(proj + (size_t)(l * HW + q) * 96 + 64 + head * 4);
        lg[l * 4 + 0] = v.x; lg[l * 4 + 1] = v.y; lg[l * 4 + 2] = v.z; lg[l * 4 + 3] = v.w;
    }
    float m = lg[0];
    #pragma unroll
    for (int i = 1; i < 12; i++) m = fmaxf(m, lg[i]);
    float w12[12], sum = 0.f;
    #pragma unroll
    for (int i = 0; i < 12; i++) { w12[i] = __expf(lg[i] - m); sum += w12[i]; }
    float inv = 1.f / sum;

    float acc[16] = {};
    #pragma unroll
    for (int l = 0; l < 3; l++) {
        float rx = ref[(size_t)(q * 3 + l) * 2 + 0] * 180.f - 0.5f;
        float ry = ref[(size_t)(q * 3 + l) * 2 + 1] * 180.f - 0.5f;
        float4 o = *(const float4*)(proj + (size_t)(l * HW + q) * 96 + head * 8 + phv * 4);
        float ox[2] = {o.x, o.z};
        float oy[2] = {o.y, o.w};

        float wqs[8];
        const uint4* vps[8];
        #pragma unroll
        for (int pp = 0; pp < 2; pp++) {
            int p = phv * 2 + pp;
            float px = rx + ox[pp];
            float py = ry + oy[pp];
            float x0f = floorf(px), y0f = floorf(py);
            int x0 = (int)x0f, y0 = (int)y0f;
            float fx = px - x0f, fy = py - y0f;
            float a = w12[l * 4 + p] * inv;
            #pragma unroll
            for (int dy = 0; dy < 2; dy++) {
                int cy = y0 + dy;
                float wy = (dy ? fy : 1.f - fy) * a;
                wy = (cy >= 0 && cy < HDIM) ? wy : 0.f;
                int cyc = min(max(cy, 0), HDIM - 1);
                #pragma unroll
                for (int dx = 0; dx < 2; dx++) {
                    int cx = x0 + dx;
                    float wq = (dx ? fx : 1.f - fx) * wy;
                    wq = (cx >= 0 && cx < HDIM) ? wq : 0.f;
                    int cxc = min(max(cx, 0), HDIM - 1);
                    int c = pp * 4 + dy * 2 + dx;
                    wqs[c] = wq;
                    vps[c] = (const uint4*)(value +
                        (((size_t)l * HW + cyc * HDIM + cxc) * CC + head * 16));
                }
            }
        }
        // issue all 16 loads back-to-back
        uint4 va[8], vb[8];
        #pragma unroll
        for (int c = 0; c < 8; c++) { va[c] = vps[c][0]; vb[c] = vps[c][1]; }
        // accumulate in the original (pp, dy, dx, d) order -> bit-identical
        #pragma unroll
        for (int c = 0; c < 8; c++) {
            float f[8];
            bf8_to_f(va[c], f);
            #pragma unroll
            for (int d = 0; d < 8; d++) acc[d] += wqs[c] * f[d];
            bf8_to_f(vb[c], f);
            #pragma unroll
            for (int d = 0; d < 8; d++) acc[8 + d] += wqs[c] * f[d];
        }
    }
    #pragma unroll
    for (int d = 0; d < 16; d++) acc[d] += __shfl_xor(acc[d], 8, 64);
    if (phv == 0) {
        u16 pack[16];
        #pragma unroll
        for (int d = 0; d < 16; d++) pack[d] = f2bf(acc[d]);
        uint4* op = (uint4*)(outp + (size_t)q * CC + head * 16);
        op[0] = ((uint4*)pack)[0];
        op[1] = ((uint4*)pack)[1];
    }
}

// ---------------------------------------------------------------------------
// FALLBACK (small workspace): fused proj + softmax + sampling (R2-proven).
// ---------------------------------------------------------------------------
__global__ __launch_bounds__(256) void sample_z(
    const u16* __restrict__ value, const u16* __restrict__ queries,
    const u16* __restrict__ woff, const u16* __restrict__ boff,
    const u16* __restrict__ wattn, const u16* __restrict__ battn,
    const float* __restrict__ ref, u16* __restrict__ outp)
{
    __shared__ u16 w_lds[128 * 96];
    __shared__ float bias_lds[96];
    const int tid = threadIdx.x;

    for (int i = tid; i < 128 * 96; i += 256) {
        int k = i / 96, c = i % 96;
        w_lds[i] = (c < 64) ? woff[k * 64 + c] : wattn[k * 32 + (c - 64)];
    }
    if (tid < 96) bias_lds[tid] = bf2f(tid < 64 ? boff[tid] : battn[tid - 64]);
    __syncthreads();

    int q = blockIdx.x * 32 + (tid >> 3);
    int head = tid & 7;
    if (q >= HW) return;

    float og[3][8], lg[12];
    #pragma unroll
    for (int l = 0; l < 3; l++) {
        const u16* qr = queries + ((size_t)l * HW + q) * CC;
        float a12[12] = {};
        #pragma unroll
        for (int kc = 0; kc < 16; kc++) {
            float f[8];
            bf8_to_f(*(const uint4*)(qr + kc * 8), f);
            #pragma unroll
            for (int j = 0; j < 8; j++) {
                const u16* wr = &w_lds[(kc * 8 + j) * 96];
                #pragma unroll
                for (int c = 0; c < 8; c++) a12[c] += f[j] * bf2f(wr[head * 8 + c]);
                #pragma unroll
                for (int c = 0; c < 4; c++) a12[8 + c] += f[j] * bf2f(wr[64 + head * 4 + c]);
            }
        }
        #pragma unroll
        for (int c = 0; c < 8; c++) og[l][c] = a12[c] + bias_lds[head * 8 + c];
        #pragma unroll
        for (int c = 0; c < 4; c++) lg[l * 4 + c] = a12[8 + c] + bias_lds[64 + head * 4 + c];
    }

    float m = lg[0];
    #pragma unroll
    for (int i = 1; i < 12; i++) m = fmaxf(m, lg[i]);
    float w12[12], sum = 0.f;
    #pragma unroll
    for (int i = 0; i < 12; i++) { w12[i] = __expf(lg[i] - m); sum += w12[i]; }
    float inv = 1.f / sum;

    float acc[16] = {};
    #pragma unroll
    for (int l = 0; l < 3; l++) {
        float rx = ref[(size_t)(q * 3 + l) * 2 + 0];
        float ry = ref[(size_t)(q * 3 + l) * 2 + 1];
        #pragma unroll
        for (int p = 0; p < 4; p++) {
            float px = rx * 180.f + og[l][p * 2 + 0] - 0.5f;
            float py = ry * 180.f + og[l][p * 2 + 1] - 0.5f;
            float x0f = floorf(px), y0f = floorf(py);
            int x0 = (int)x0f, y0 = (int)y0f;
            float fx = px - x0f, fy = py - y0f;
            float a = w12[l * 4 + p] * inv;
            #pragma unroll
            for (int dy = 0; dy < 2; dy++) {
                int cy = y0 + dy;
                if (cy < 0 || cy >= HDIM) continue;
                #pragma unroll
                for (int dx = 0; dx < 2; dx++) {
                    int cx = x0 + dx;
                    if (cx < 0 || cx >= HDIM) continue;
                    float wq = a * ((dx ? fx : 1.f - fx) * (dy ? fy : 1.f - fy));
                    const uint4* vp = (const uint4*)(value + (((size_t)l * HW + cy * HDIM + cx) * CC + head * 16));
                    uint4 va = vp[0], vb = vp[1];
                    float f[8];
                    bf8_to_f(va, f);
                    #pragma unroll
                    for (int d = 0; d < 8; d++) acc[d] += wq * f[d];
                    bf8_to_f(vb, f);
                    #pragma unroll
                    for (int d = 0; d < 8; d++) acc[8 + d] += wq * f[d];
                }
            }
        }
    }
    u16 pack[16];
    #pragma unroll
    for (int d = 0; d < 16; d++) pack[d] = f2bf(acc[d]);
    uint4* op = (uint4*)(outp + (size_t)q * CC + head * 16);
    op[0] = ((uint4*)pack)[0];
    op[1] = ((uint4*)pack)[1];
}

// LayerNorm in place, bf16 buffer (fallback path)
__global__ __launch_bounds__(256) void ln_z(
    u16* __restrict__ x, const u16* __restrict__ g, const u16* __restrict__ b, int M)
{
    int row = blockIdx.x * 4 + (threadIdx.x >> 6);
    int lane = threadIdx.x & 63;
    if (row >= M) return;
    u16* xr = x + (size_t)row * 128;
    float v0 = bf2f(xr[lane]), v1 = bf2f(xr[lane + 64]);
    float s = v0 + v1;
    #pragma unroll
    for (int o = 32; o; o >>= 1) s += __shfl_xor(s, o, 64);
    float mean = s * (1.f / 128.f);
    float d0 = v0 - mean, d1 = v1 - mean;
    float vs = d0 * d0 + d1 * d1;
    #pragma unroll
    for (int o = 32; o; o >>= 1) vs += __shfl_xor(vs, o, 64);
    float r = rsqrtf(vs * (1.f / 128.f) + 1e-5f);
    xr[lane]      = f2bf(d0 * r * bf2f(g[lane])      + bf2f(b[lane]));
    xr[lane + 64] = f2bf(d1 * r * bf2f(g[lane + 64]) + bf2f(b[lane + 64]));
}

// LayerNorm in place, FLOAT32 buffer (fallback path)
__global__ __launch_bounds__(256) void ln32_z(
    float* __restrict__ x, const u16* __restrict__ g, const u16* __restrict__ b, int M)
{
    int row = blockIdx.x * 4 + (threadIdx.x >> 6);
    int lane = threadIdx.x & 63;
    if (row >= M) return;
    float* xr = x + (size_t)row * 128;
    float v0 = xr[lane], v1 = xr[lane + 64];
    float s = v0 + v1;
    #pragma unroll
    for (int o = 32; o; o >>= 1) s += __shfl_xor(s, o, 64);
    float mean = s * (1.f / 128.f);
    float d0 = v0 - mean, d1 = v1 - mean;
    float vs = d0 * d0 + d1 * d1;
    #pragma unroll
    for (int o = 32; o; o >>= 1) vs += __shfl_xor(vs, o, 64);
    float r = rsqrtf(vs * (1.f / 128.f) + 1e-5f);
    xr[lane]      = d0 * r * bf2f(g[lane])      + bf2f(b[lane]);
    xr[lane + 64] = d1 * r * bf2f(g[lane + 64]) + bf2f(b[lane + 64]);
}

extern "C" void kernel_launch(void* const* d_in, const int* in_sizes, int n_in,
                              void* d_out, int out_size, void* d_ws, size_t ws_size,
                              hipStream_t stream)
{
    char* ws = (char*)d_ws;
    u16* canon   = (u16*)ws;                      // 26,480,512 B
    u16* value   = (u16*)(ws + 26480512);         // 24,883,200 B
    u16* queries = (u16*)(ws + 51363712);         // 24,883,200 B
    u16* src     = (u16*)(ws + 26480512);         // aliases dead value (8.3 MB)
    float* dout  = (float*)d_out;                 // FLOAT32 output

    const size_t PROJ_OFF = 76246912;
    const size_t PROJ_END = PROJ_OFF + (size_t)3 * HW * 96 * 4;   // 113,571,712
    const bool big = ws_size >= PROJ_END;
    float* proj  = (float*)(ws + PROJ_OFF);
    u16* wtbuf   = (u16*)(ws + PROJ_OFF);         // conv wt (590 KB), dead before proj
    f32x4v* q0   = (f32x4v*)(ws + PROJ_OFF + 1048576);  // ~16.7 MB, inside proj region
    u16* out_s   = big ? (u16*)(ws + 51363712) : (u16*)(ws + 76246912);
    u16* hidden  = (u16*)(ws + 51363712);         // FFN hidden, 33.2 MB/stripe (2 stripes)

    // MFMA-GEMM transposed weights:
    u16* WvalT = (u16*)(ws + 51363712);           // queries region, pre-conv (32 KB)
    u16* W1T   = (u16*)(ws + 34774912);           // value tail after src (256 KB)
    u16* W2T   = (u16*)(ws + 35037056);           // value tail (256 KB)
    u16* wcatT = (u16*)d_out;                     // d_out scratch, dead until FFN2
    u16* b128  = (u16*)d_out + 16384;
    u16* WoutT = (u16*)d_out + 32768;             // d_out scratch (32 KB)

    // locate weight base: conv_w has unique element count 294912
    int i_cw = 2;
    while (i_cw < n_in - 17 && in_sizes[i_cw] != 294912) i_cw++;
    if (i_cw >= n_in - 17) i_cw = 3;

    PtrsZ ptrs;
    ptrs.p[0] = d_in[0];                // src_all
    ptrs.p[1] = d_in[1];                // reference_points
    for (int i = 0; i < 18; i++) ptrs.p[2 + i] = d_in[i_cw + i];

    const u16* csrc  = canon + CAN_SRC;
    const u16* ccw   = canon + CAN_CW;
    const u16* ccb   = canon + CAN_CB;
    const u16* cWval = canon + CAN_WVAL,  *cbval = canon + CAN_BVAL;
    const u16* cWoff = canon + CAN_WOFF,  *cboff = canon + CAN_BOFF;
    const u16* cWatt = canon + CAN_WATTN, *cbatt = canon + CAN_BATTN;
    const u16* cWout = canon + CAN_WOUT,  *cbout = canon + CAN_BOUT;
    const u16* cg1   = canon + CAN_LN1G,  *cb1n  = canon + CAN_LN1B;
    const u16* cW1   = canon + CAN_W1,    *cbf1  = canon + CAN_B1;
    const u16* cW2   = canon + CAN_W2,    *cbf2  = canon + CAN_B2;
    const u16* cg2   = canon + CAN_LN2G,  *cb2n  = canon + CAN_LN2B;

    convert_z<<<dim3((CAN_TOTAL + 255) / 256), 256, 0, stream>>>(ptrs, canon);

    const int M3 = 3 * HW, M1 = HW;

    if (big) {
        // prep: conv-wt + WvalT + Wcat/b128 + WoutT (one launch)
        prep1_z<<<dim3((344192 + 255) / 256), 256, 0, stream>>>(
            ccw, cWval, cWout, cWoff, cWatt, cboff, cbatt,
            wtbuf, WvalT, wcatT, b128, WoutT);
        // 1. value = src_all @ W_val + b_val
        gemmm_z<1, false, false, false><<<dim3(1, 1519), 256, 0, stream>>>(
            csrc, WvalT, cbval, value, nullptr, nullptr, nullptr, M3, 128, 128, 128);
        // 2. conv -> queries, half-factored:
        //    2a. frame-0 half once (2 sub-tiles, grid 254 balanced) -> q0
        convh0_z<<<dim3((HW + 127) / 128), 256, 0, stream>>>(csrc, wtbuf, q0);
        //    2b. per-l half (3 sub-tiles named vars, grid 507 ~ 2/CU) -> queries
        convh1_z<<<dim3((HW + 191) / 192, 3), 256, 0, stream>>>(
            csrc, wtbuf, ccb, q0, queries);
        // 3a. proj[M3][96] f32 = queries @ WcatT + bias128 (overwrites wtbuf/q0)
        gemmm_z<0, false, false, false><<<dim3(1, 1519), 256, 0, stream>>>(
            queries, wcatT, b128, proj, nullptr, nullptr, nullptr, M3, 128, 96, 96);
        // 3b. sampling (hoisted gathers) -> out_s
        sample3_z<<<dim3((HW + 15) / 16), 256, 0, stream>>>(
            value, proj, (const float*)d_in[1], out_s);
        // value now dead -> W1T/W2T in its tail
        w12t_z<<<dim3(1024), 256, 0, stream>>>(cW1, cW2, W1T, W2T);
        // 4. src = LN1(out_s @ W_out + b_out + src_all[0])  [LN fused]
        gemmm_z<1, false, true, true><<<dim3(1, 507), 256, 0, stream>>>(
            out_s, WoutT, cbout, src, csrc, cg1, cb1n, M1, 128, 128, 128);
        // 5-6. FFN in 2 stripes; FFN2 fuses residual + LN2, writes f32 d_out
        for (int sblk = 0; sblk < 2; sblk++) {
            const u16* srow = src + (size_t)sblk * 16200 * 128;
            float* drow = dout + (size_t)sblk * 16200 * 128;
            gemmm_z<1, true, false, false><<<dim3(8, 254), 256, 0, stream>>>(
                srow, W1T, cbf1, hidden, nullptr, nullptr, nullptr, 16200, 128, 1024, 1024);
            gemmm_z<0, false, true, true><<<dim3(1, 254), 256, 0, stream>>>(
                hidden, W2T, cbf2, drow, srow, cg2, cb2n, 16200, 1024, 128, 128);
        }
    } else {
        // --- fallback: R2-proven VALU path ---
        u16* out_f = (u16*)(ws + 76246912);
        u16* hid_f = (u16*)(ws + 51363712);
        gemm_z<true, false, false><<<dim3(2, 1519), 256, 0, stream>>>(
            csrc, cWval, cbval, value, nullptr, M3, 128, 128);
        conv_z<<<dim3(9, 45, 3), 256, 0, stream>>>(csrc, ccw, ccb, queries);
        sample_z<<<dim3(1013), 256, 0, stream>>>(
            value, queries, cWoff, cboff, cWatt, cbatt, (const float*)d_in[1], out_f);
        gemm_z<true, false, true><<<dim3(2, 507), 256, 0, stream>>>(
            out_f, cWout, cbout, src, csrc, M1, 128, 128);
        ln_z<<<dim3(8100), 256, 0, stream>>>(src, cg1, cb1n, M1);
        for (int sblk = 0; sblk < 4; sblk++) {
            const u16* srow = src + (size_t)sblk * 8100 * 128;
            float* drow = dout + (size_t)sblk * 8100 * 128;
            gemm_z<true, true, false><<<dim3(16, 127), 256, 0, stream>>>(
                srow, cW1, cbf1, hid_f, nullptr, 8100, 1024, 128);
            gemm_z<false, false, true><<<dim3(2, 127), 256, 0, stream>>>(
                hid_f, cW2, cbf2, drow, srow, 8100, 128, 1024);
        }
        ln32_z<<<dim3(8100), 256, 0, stream>>>(dout, cg2, cb2n, M1);
    }
}